// Round 3
// baseline (376.323 us; speedup 1.0000x reference)
//
#include <hip/hip_runtime.h>

#define B_ 128
#define T_ 256
#define H_ 768
#define K_ 64
#define BT_ (B_ * T_)

// ---------------------------------------------------------------------------
// DPP helpers: wave-wide max in ~6 VALU ops (row_shr/bcast ladder).
// ---------------------------------------------------------------------------
template <int CTRL>
__device__ __forceinline__ float dpp_mov_f(float x) {
    return __int_as_float(__builtin_amdgcn_update_dpp(
        __float_as_int(x), __float_as_int(x), CTRL, 0xF, 0xF, false));
}
__device__ __forceinline__ float wave_max64(float x) {
    x = fmaxf(x, dpp_mov_f<0x111>(x));  // row_shr:1
    x = fmaxf(x, dpp_mov_f<0x112>(x));  // row_shr:2
    x = fmaxf(x, dpp_mov_f<0x114>(x));  // row_shr:4
    x = fmaxf(x, dpp_mov_f<0x118>(x));  // row_shr:8
    x = fmaxf(x, dpp_mov_f<0x142>(x));  // row_bcast:15
    x = fmaxf(x, dpp_mov_f<0x143>(x));  // row_bcast:31
    return __int_as_float(__builtin_amdgcn_readlane(__float_as_int(x), 63));
}
__device__ __forceinline__ float readlane0_f(float x) {
    return __int_as_float(__builtin_amdgcn_readfirstlane(__float_as_int(x)));
}
template <int I>
__device__ __forceinline__ float readlane_f(float x) {
    return __int_as_float(__builtin_amdgcn_readlane(__float_as_int(x), I));
}

// ---------------------------------------------------------------------------
// Kernel A: emissions = hidden @ W + b.  (round-2 version, ~near roofline:
// BM=64 tiles, 512 blocks x 256 thr -> 2 blocks/CU. Cross-round accounting
// shows gemm ~30-40us; not the lever. Unchanged.)
// ---------------------------------------------------------------------------
#define BK_ 32
#define BM_ 64
#define P_ 66
__global__ __launch_bounds__(256) void gemm_emis(const float* __restrict__ hidden,
                                                 const float* __restrict__ W,
                                                 const float* __restrict__ bias,
                                                 float* __restrict__ emis) {
    __shared__ float At[BK_ * P_];

    const int tid = threadIdx.x;
    const int lane = tid & 63;
    const int wc = __builtin_amdgcn_readfirstlane((tid >> 6) * 16);
    const int rowbase = blockIdx.x * BM_;
    const int srow = tid >> 2;
    const int scol = (tid & 3) * 8;

    float acc[16];
#pragma unroll
    for (int c = 0; c < 16; ++c) acc[c] = bias[wc + c];

    float4 pf0 = *(const float4*)&hidden[(size_t)(rowbase + srow) * H_ + scol];
    float4 pf1 = *(const float4*)&hidden[(size_t)(rowbase + srow) * H_ + scol + 4];

    for (int kb = 0; kb < H_ / BK_; ++kb) {
        __syncthreads();
        At[(scol + 0) * P_ + srow] = pf0.x;
        At[(scol + 1) * P_ + srow] = pf0.y;
        At[(scol + 2) * P_ + srow] = pf0.z;
        At[(scol + 3) * P_ + srow] = pf0.w;
        At[(scol + 4) * P_ + srow] = pf1.x;
        At[(scol + 5) * P_ + srow] = pf1.y;
        At[(scol + 6) * P_ + srow] = pf1.z;
        At[(scol + 7) * P_ + srow] = pf1.w;
        __syncthreads();
        if (kb + 1 < H_ / BK_) {
            pf0 = *(const float4*)&hidden[(size_t)(rowbase + srow) * H_ +
                                          (kb + 1) * BK_ + scol];
            pf1 = *(const float4*)&hidden[(size_t)(rowbase + srow) * H_ +
                                          (kb + 1) * BK_ + scol + 4];
        }
        const float* Wk = &W[(kb * BK_) * K_ + wc];
#pragma unroll 8
        for (int h = 0; h < BK_; ++h) {
            float a = At[h * P_ + lane];
            float4 w0 = *(const float4*)&Wk[h * K_ + 0];
            float4 w1 = *(const float4*)&Wk[h * K_ + 4];
            float4 w2 = *(const float4*)&Wk[h * K_ + 8];
            float4 w3 = *(const float4*)&Wk[h * K_ + 12];
            acc[0]  += a * w0.x;  acc[1]  += a * w0.y;
            acc[2]  += a * w0.z;  acc[3]  += a * w0.w;
            acc[4]  += a * w1.x;  acc[5]  += a * w1.y;
            acc[6]  += a * w1.z;  acc[7]  += a * w1.w;
            acc[8]  += a * w2.x;  acc[9]  += a * w2.y;
            acc[10] += a * w2.z;  acc[11] += a * w2.w;
            acc[12] += a * w3.x;  acc[13] += a * w3.y;
            acc[14] += a * w3.z;  acc[15] += a * w3.w;
        }
    }

    float* e = &emis[(size_t)(rowbase + lane) * K_ + wc];
#pragma unroll
    for (int q = 0; q < 4; ++q)
        *(float4*)&e[q * 4] = make_float4(acc[q * 4], acc[q * 4 + 1],
                                          acc[q * 4 + 2], acc[q * 4 + 3]);
}

// ---------------------------------------------------------------------------
// Kernel B: fused CRF.  Round 3: same structure as round 0 (142us), but both
// serial inner loops restructured into DOUBLE-BUFFERED GROUPS OF 8 readlanes.
// Rationale: 142us / 255 steps = ~1337 cy/step for ~136 mostly-independent
// VALU ops = ~9 cy/instr. Source order readlane->fma back-to-back exposes the
// VALU-writes-SGPR -> VALU-reads-SGPR RAW hazard on every consumer. Grouped
// double-buffering guarantees every SGPR is consumed >=8 instructions after
// its producer. Accumulation mapping/order preserved exactly (a0 <- i=0,8,..,
// 56; m0 <- pairs (0,1),(8,9),..) -> bit-identical results.
// ---------------------------------------------------------------------------
__global__ __launch_bounds__(128, 1) void crf_kernel(const float* __restrict__ emis,
                                                     const int* __restrict__ masks,
                                                     const int* __restrict__ target,
                                                     const float* __restrict__ trans,
                                                     float* __restrict__ out) {
    __shared__ __align__(16) float ebuf[T_ * K_];   // 64 KB emissions for batch b
    __shared__ __align__(16) float vbuf[T_ * K_];   // 64 KB viterbi v-history
    __shared__ float tbuf[K_ * 65];                 // padded trans rows (backtrack)

    const int tid = threadIdx.x;
    const int lane = tid & 63;
    const int b = blockIdx.x;
    const float* eb = emis + (size_t)b * (T_ * K_);

    // stage emissions: 4096 float4s over 128 threads
    {
        const float4* src = (const float4*)eb;
        float4* dst = (float4*)ebuf;
#pragma unroll
        for (int k = 0; k < 32; ++k) dst[tid + k * 128] = src[tid + k * 128];
    }
    int sl = 0;
#pragma unroll
    for (int k = 0; k < 4; ++k) sl += masks[b * T_ + lane + k * 64];
#pragma unroll
    for (int m = 32; m; m >>= 1) sl += __shfl_xor(sl, m, 64);
    const int seq_len = sl;
    __syncthreads();

    if (tid < 64) {
        // ================= forward (wave 0), delayed normalization ==========
        float Ecol[64];
#pragma unroll
        for (int i = 0; i < 64; ++i) Ecol[i] = __expf(trans[i * K_ + lane]);

        float e_c = ebuf[lane];
        float e00 = readlane0_f(e_c);
        float p = __expf(e_c - e00);     // e^{alpha_0} = p * e^C
        float C = e00;
        float logD0prev = 0.f;
        float e_n = ebuf[K_ + lane];
        float en0 = readlane0_f(e_n);
        float xg = __expf(e_n - en0);    // x * g

        for (int t = 1; t < T_; ++t) {
            float e_f = (t < T_ - 1) ? ebuf[(t + 1) * K_ + lane] : 0.f;
            float a0 = 0.f, a1 = 0.f, a2 = 0.f, a3 = 0.f;
            float a4 = 0.f, a5 = 0.f, a6 = 0.f, a7 = 0.f;
            float bufA[8], bufB[8];
            // grouped readlanes (8-deep double buffer): producer-consumer
            // distance >= 8 instructions -> SGPR RAW hazard hidden.
#define RL8(buf, vv, base)                              \
            buf[0] = readlane_f<(base) + 0>(vv);        \
            buf[1] = readlane_f<(base) + 1>(vv);        \
            buf[2] = readlane_f<(base) + 2>(vv);        \
            buf[3] = readlane_f<(base) + 3>(vv);        \
            buf[4] = readlane_f<(base) + 4>(vv);        \
            buf[5] = readlane_f<(base) + 5>(vv);        \
            buf[6] = readlane_f<(base) + 6>(vv);        \
            buf[7] = readlane_f<(base) + 7>(vv);
#define FMA8(buf, base)                                 \
            a0 = fmaf(buf[0], Ecol[(base) + 0], a0);    \
            a1 = fmaf(buf[1], Ecol[(base) + 1], a1);    \
            a2 = fmaf(buf[2], Ecol[(base) + 2], a2);    \
            a3 = fmaf(buf[3], Ecol[(base) + 3], a3);    \
            a4 = fmaf(buf[4], Ecol[(base) + 4], a4);    \
            a5 = fmaf(buf[5], Ecol[(base) + 5], a5);    \
            a6 = fmaf(buf[6], Ecol[(base) + 6], a6);    \
            a7 = fmaf(buf[7], Ecol[(base) + 7], a7);
            RL8(bufA, p, 0)
            RL8(bufB, p, 8)
            FMA8(bufA, 0)   RL8(bufA, p, 16)
            FMA8(bufB, 8)   RL8(bufB, p, 24)
            FMA8(bufA, 16)  RL8(bufA, p, 32)
            FMA8(bufB, 24)  RL8(bufB, p, 40)
            FMA8(bufA, 32)  RL8(bufA, p, 48)
            FMA8(bufB, 40)  RL8(bufB, p, 56)
            FMA8(bufA, 48)
            FMA8(bufB, 56)
#undef FMA8
            float D = ((a0 + a1) + (a2 + a3)) + ((a4 + a5) + (a6 + a7));
            float pnew = D * xg;         // only on-chain op after the dot
            if (t < seq_len) { p = pnew; C += en0 + logD0prev; }
            // off-chain prep for next step
            float D0 = readlane0_f(D);
            logD0prev = __logf(D0);
            float gn = __fdividef(1.f, D0);
            en0 = readlane0_f(e_f);
            xg = __expf(e_f - en0) * gn;
            e_n = e_f;
        }
        float rs = p;
#pragma unroll
        for (int m = 32; m; m >>= 1) rs += __shfl_xor(rs, m, 64);
        float log_norm = C + __logf(rs);

        // ---------------- sequence score ----------------
        float sc = 0.f;
#pragma unroll
        for (int k = 0; k < 4; ++k) {
            int t = lane + k * 64;
            if (t < seq_len) {
                int tg = target[b * T_ + t];
                sc += ebuf[t * K_ + tg];
                if (t >= 1) sc += trans[target[b * T_ + t - 1] * K_ + tg];
            }
        }
#pragma unroll
        for (int m = 32; m; m >>= 1) sc += __shfl_xor(sc, m, 64);
        if (lane == 0) out[BT_ + b] = sc - log_norm;
    } else {
        // ================= Viterbi (wave 1): readlane max-plus ==============
        float Tcol[64];
#pragma unroll
        for (int i = 0; i < 64; ++i) Tcol[i] = trans[i * K_ + lane];
        for (int idx = lane; idx < K_ * K_; idx += 64)
            tbuf[(idx >> 6) * 65 + (idx & 63)] = trans[idx];

        float v = ebuf[lane];
        vbuf[lane] = v;
        float e_n = ebuf[K_ + lane];
        for (int t = 1; t < T_; ++t) {
            float e_f = (t < T_ - 1) ? ebuf[(t + 1) * K_ + lane] : 0.f;
            float m0 = -3.4e38f, m1 = -3.4e38f, m2 = -3.4e38f, m3 = -3.4e38f;
            float bufA[8], bufB[8];
            // same grouped double-buffer; pairs -> max3 (exact regroup,
            // validated r1/r2). m0 <- (base+0,base+1) for base=0,8,..,56.
#define MAX8(buf, base)                                                        \
            m0 = fmaxf(fmaxf(m0, buf[0] + Tcol[(base) + 0]),                   \
                       buf[1] + Tcol[(base) + 1]);                             \
            m1 = fmaxf(fmaxf(m1, buf[2] + Tcol[(base) + 2]),                   \
                       buf[3] + Tcol[(base) + 3]);                             \
            m2 = fmaxf(fmaxf(m2, buf[4] + Tcol[(base) + 4]),                   \
                       buf[5] + Tcol[(base) + 5]);                             \
            m3 = fmaxf(fmaxf(m3, buf[6] + Tcol[(base) + 6]),                   \
                       buf[7] + Tcol[(base) + 7]);
            RL8(bufA, v, 0)
            RL8(bufB, v, 8)
            MAX8(bufA, 0)   RL8(bufA, v, 16)
            MAX8(bufB, 8)   RL8(bufB, v, 24)
            MAX8(bufA, 16)  RL8(bufA, v, 32)
            MAX8(bufB, 24)  RL8(bufB, v, 40)
            MAX8(bufA, 32)  RL8(bufA, v, 48)
            MAX8(bufB, 40)  RL8(bufB, v, 56)
            MAX8(bufA, 48)
            MAX8(bufB, 56)
#undef MAX8
#undef RL8
            float M = fmaxf(fmaxf(m0, m1), fmaxf(m2, m3));
            float vn = M + e_n;
            if (t < seq_len) v = vn;
            vbuf[t * K_ + lane] = v;   // off-chain ds_write (history)
            e_n = e_f;
        }

        // last tag: first index of max over lanes (np.argmax tie rule)
        float M = wave_max64(v);
        unsigned long long ball = __ballot(v >= M);
        int tag = (int)__builtin_ctzll(ball);

        int path[4];
#pragma unroll
        for (int k = 0; k < 4; ++k) path[k] = 0;
        if (lane == ((T_ - 1) & 63)) path[(T_ - 1) >> 6] = tag;

        float vpre = vbuf[(T_ - 2) * K_ + lane];
        for (int t = T_ - 1; t >= 1; --t) {
            float vnext = (t >= 2) ? vbuf[(t - 2) * K_ + lane] : 0.f;
            if (t < seq_len) {
                float s = vpre + tbuf[lane * 65 + tag];
                float Ms = wave_max64(s);
                unsigned long long bl = __ballot(s >= Ms);
                tag = (int)__builtin_ctzll(bl);
            }
            int pidx = t - 1;
            if (lane == (pidx & 63)) path[pidx >> 6] = tag;
            vpre = vnext;
        }
#pragma unroll
        for (int k = 0; k < 4; ++k) {
            int t = lane + k * 64;
            out[b * T_ + t] = (t < seq_len) ? (float)path[k] : 0.f;
        }
    }
}

// ---------------------------------------------------------------------------
extern "C" void kernel_launch(void* const* d_in, const int* in_sizes, int n_in,
                              void* d_out, int out_size, void* d_ws, size_t ws_size,
                              hipStream_t stream) {
    const float* hidden = (const float*)d_in[0];
    const int* masks    = (const int*)d_in[1];
    const int* target   = (const int*)d_in[2];
    const float* W      = (const float*)d_in[3];
    const float* bias   = (const float*)d_in[4];
    const float* trans  = (const float*)d_in[5];
    float* out = (float*)d_out;
    float* emis = (float*)d_ws;

    gemm_emis<<<dim3(BT_ / BM_), dim3(256), 0, stream>>>(hidden, W, bias, emis);
    crf_kernel<<<dim3(B_), dim3(128), 0, stream>>>(emis, masks, target, trans, out);
}

// Round 4
// 366.890 us; speedup vs baseline: 1.0257x; 1.0257x over previous
//
#include <hip/hip_runtime.h>

#define B_ 128
#define T_ 256
#define H_ 768
#define K_ 64
#define BT_ (B_ * T_)

// ---------------------------------------------------------------------------
// DPP helpers. quad_perm 0xB1 = lane^1, 0x4E = lane^2 (pure VALU, 1-op).
// ---------------------------------------------------------------------------
template <int CTRL>
__device__ __forceinline__ float dpp_mov_f(float x) {
    return __int_as_float(__builtin_amdgcn_update_dpp(
        __float_as_int(x), __float_as_int(x), CTRL, 0xF, 0xF, false));
}
__device__ __forceinline__ float wave_max64(float x) {
    x = fmaxf(x, dpp_mov_f<0x111>(x));  // row_shr:1
    x = fmaxf(x, dpp_mov_f<0x112>(x));  // row_shr:2
    x = fmaxf(x, dpp_mov_f<0x114>(x));  // row_shr:4
    x = fmaxf(x, dpp_mov_f<0x118>(x));  // row_shr:8
    x = fmaxf(x, dpp_mov_f<0x142>(x));  // row_bcast:15
    x = fmaxf(x, dpp_mov_f<0x143>(x));  // row_bcast:31
    return __int_as_float(__builtin_amdgcn_readlane(__float_as_int(x), 63));
}

// ---------------------------------------------------------------------------
// Kernel A: emissions = hidden @ W + b.  (round-2 version, ~near roofline;
// unchanged — cross-round accounting shows gemm is not the lever.)
// ---------------------------------------------------------------------------
#define BK_ 32
#define BM_ 64
#define P_ 66
__global__ __launch_bounds__(256) void gemm_emis(const float* __restrict__ hidden,
                                                 const float* __restrict__ W,
                                                 const float* __restrict__ bias,
                                                 float* __restrict__ emis) {
    __shared__ float At[BK_ * P_];

    const int tid = threadIdx.x;
    const int lane = tid & 63;
    const int wc = __builtin_amdgcn_readfirstlane((tid >> 6) * 16);
    const int rowbase = blockIdx.x * BM_;
    const int srow = tid >> 2;
    const int scol = (tid & 3) * 8;

    float acc[16];
#pragma unroll
    for (int c = 0; c < 16; ++c) acc[c] = bias[wc + c];

    float4 pf0 = *(const float4*)&hidden[(size_t)(rowbase + srow) * H_ + scol];
    float4 pf1 = *(const float4*)&hidden[(size_t)(rowbase + srow) * H_ + scol + 4];

    for (int kb = 0; kb < H_ / BK_; ++kb) {
        __syncthreads();
        At[(scol + 0) * P_ + srow] = pf0.x;
        At[(scol + 1) * P_ + srow] = pf0.y;
        At[(scol + 2) * P_ + srow] = pf0.z;
        At[(scol + 3) * P_ + srow] = pf0.w;
        At[(scol + 4) * P_ + srow] = pf1.x;
        At[(scol + 5) * P_ + srow] = pf1.y;
        At[(scol + 6) * P_ + srow] = pf1.z;
        At[(scol + 7) * P_ + srow] = pf1.w;
        __syncthreads();
        if (kb + 1 < H_ / BK_) {
            pf0 = *(const float4*)&hidden[(size_t)(rowbase + srow) * H_ +
                                          (kb + 1) * BK_ + scol];
            pf1 = *(const float4*)&hidden[(size_t)(rowbase + srow) * H_ +
                                          (kb + 1) * BK_ + scol + 4];
        }
        const float* Wk = &W[(kb * BK_) * K_ + wc];
#pragma unroll 8
        for (int h = 0; h < BK_; ++h) {
            float a = At[h * P_ + lane];
            float4 w0 = *(const float4*)&Wk[h * K_ + 0];
            float4 w1 = *(const float4*)&Wk[h * K_ + 4];
            float4 w2 = *(const float4*)&Wk[h * K_ + 8];
            float4 w3 = *(const float4*)&Wk[h * K_ + 12];
            acc[0]  += a * w0.x;  acc[1]  += a * w0.y;
            acc[2]  += a * w0.z;  acc[3]  += a * w0.w;
            acc[4]  += a * w1.x;  acc[5]  += a * w1.y;
            acc[6]  += a * w1.z;  acc[7]  += a * w1.w;
            acc[8]  += a * w2.x;  acc[9]  += a * w2.y;
            acc[10] += a * w2.z;  acc[11] += a * w2.w;
            acc[12] += a * w3.x;  acc[13] += a * w3.y;
            acc[14] += a * w3.z;  acc[15] += a * w3.w;
        }
    }

    float* e = &emis[(size_t)(rowbase + lane) * K_ + wc];
#pragma unroll
    for (int q = 0; q < 4; ++q)
        *(float4*)&e[q * 4] = make_float4(acc[q * 4], acc[q * 4 + 1],
                                          acc[q * 4 + 2], acc[q * 4 + 3]);
}

// ---------------------------------------------------------------------------
// Kernel B: fused CRF.  Round 4: DISTRIBUTED scan — r3 proved the 64-wide
// readlane all-to-all is throughput-bound (~16cy/readlane; reorder had no
// effect), so eliminate it. 8 waves: waves 0-3 forward, 4-7 viterbi. Lane
// layout lane=jl*4+q: owns state j=16*wave+jl, reduces source quarter
// i in [16q,16q+16). Per step: 4 batched ds_read_b128 (one latency, not 64
// crossbar ops) + 16 fma/max + 2 quad_perm DPP combine + 1 barrier; p/v
// vectors double-buffered in LDS. Viterbi decode bit-identical (max is
// associative, tie rule and backtrack unchanged); log-norm dot reordered
// (within the tolerance already absorbed by fast-math exp/log).
// ---------------------------------------------------------------------------
__global__ __launch_bounds__(512, 1) void crf_kernel(const float* __restrict__ emis,
                                                     const int* __restrict__ masks,
                                                     const int* __restrict__ target,
                                                     const float* __restrict__ trans,
                                                     float* __restrict__ out) {
    __shared__ __align__(16) float ebuf[T_ * K_];    // 64 KB emissions
    __shared__ __align__(16) float vhist[T_ * K_];   // 64 KB viterbi history
    __shared__ float tbuf[K_ * 65];                  // padded trans (backtrack)
    __shared__ __align__(16) float pbuf[2][K_];      // fwd p double-buffer
    __shared__ __align__(16) float vstep[2][K_];     // vit v double-buffer
    __shared__ float sbuf[2];                        // D0 scalar double-buffer
    __shared__ float red[8];                         // cross-wave reduce

    const int tid = threadIdx.x;
    const int lane = tid & 63;
    const int wv = tid >> 6;           // 0..7
    const bool fwd = (wv < 4);
    const int wq = fwd ? wv : (wv - 4);
    const int q = lane & 3;            // source quarter
    const int jl = lane >> 2;          // local state
    const int j = wq * 16 + jl;        // owned global state
    const int q16 = q * 16;
    const int b = blockIdx.x;
    const float* eb = emis + (size_t)b * (T_ * K_);

    // stage emissions: 4096 float4s over 512 threads
    {
        const float4* src = (const float4*)eb;
        float4* dst = (float4*)ebuf;
#pragma unroll
        for (int k = 0; k < 8; ++k) dst[tid + k * 512] = src[tid + k * 512];
    }
    int sl = 0;
#pragma unroll
    for (int k = 0; k < 4; ++k) sl += masks[b * T_ + lane + k * 64];
#pragma unroll
    for (int m = 32; m; m >>= 1) sl += __shfl_xor(sl, m, 64);
    const int seq_len = sl;

    // per-lane transition slice: i in [16q,16q+16), fixed j
    float Eq[16];
#pragma unroll
    for (int ii = 0; ii < 16; ++ii) {
        float tv = trans[(q16 + ii) * K_ + j];
        Eq[ii] = fwd ? __expf(tv) : tv;
    }
    if (wv == 4)
        for (int idx = lane; idx < K_ * K_; idx += 64)
            tbuf[(idx >> 6) * 65 + (idx & 63)] = trans[idx];
    __syncthreads();   // ebuf ready

    // ---- t = 0 init ----
    float C = 0.f, p = 0.f, v = 0.f;
    if (fwd) {
        float e00 = ebuf[0];
        p = __expf(ebuf[j] - e00);     // e^{alpha_0} = p * e^C
        C = e00;
        if (q == 0) pbuf[0][j] = p;
        if (tid == 0) sbuf[0] = 1.0f;  // D0prev=1: log->0, rcp->1, both exact
    } else {
        v = ebuf[j];
        if (q == 0) { vstep[0][j] = v; vhist[j] = v; }
    }
    __syncthreads();   // pbuf[0]/vstep[0]/sbuf[0] published

    for (int t = 1; t < T_; ++t) {
        const int rp = (t - 1) & 1, wp = t & 1;
        if (fwd) {
            const float* pb = pbuf[rp];
            float4 P0 = *(const float4*)&pb[q16 + 0];
            float4 P1 = *(const float4*)&pb[q16 + 4];
            float4 P2 = *(const float4*)&pb[q16 + 8];
            float4 P3 = *(const float4*)&pb[q16 + 12];
            float D0p = sbuf[rp];
            float et0 = ebuf[t * K_];
            float etj = ebuf[t * K_ + j];
            float xg = __expf(etj - et0) * __fdividef(1.f, D0p);
            float s0 = P0.x * Eq[0];     s0 = fmaf(P0.y, Eq[1], s0);
            s0 = fmaf(P0.z, Eq[2], s0);  s0 = fmaf(P0.w, Eq[3], s0);
            float s1 = P1.x * Eq[4];     s1 = fmaf(P1.y, Eq[5], s1);
            s1 = fmaf(P1.z, Eq[6], s1);  s1 = fmaf(P1.w, Eq[7], s1);
            float s2 = P2.x * Eq[8];     s2 = fmaf(P2.y, Eq[9], s2);
            s2 = fmaf(P2.z, Eq[10], s2); s2 = fmaf(P2.w, Eq[11], s2);
            float s3 = P3.x * Eq[12];    s3 = fmaf(P3.y, Eq[13], s3);
            s3 = fmaf(P3.z, Eq[14], s3); s3 = fmaf(P3.w, Eq[15], s3);
            float part = (s0 + s1) + (s2 + s3);
            float u = part + dpp_mov_f<0xB1>(part);  // + partner q^1
            float D = u + dpp_mov_f<0x4E>(u);        // + partner q^2
            float pnew = D * xg;
            if (t < seq_len) { p = pnew; C += et0 + __logf(D0p); }
            if (q == 0) pbuf[wp][j] = p;
            if (tid == 0) sbuf[wp] = D;   // D[0]: wave0, jl=0, q=0
        } else {
            const float* vb = vstep[rp];
            float4 V0 = *(const float4*)&vb[q16 + 0];
            float4 V1 = *(const float4*)&vb[q16 + 4];
            float4 V2 = *(const float4*)&vb[q16 + 8];
            float4 V3 = *(const float4*)&vb[q16 + 12];
            float etj = ebuf[t * K_ + j];
            float mA = fmaxf(fmaxf(V0.x + Eq[0],  V0.y + Eq[1]),
                             fmaxf(V0.z + Eq[2],  V0.w + Eq[3]));
            float mB = fmaxf(fmaxf(V1.x + Eq[4],  V1.y + Eq[5]),
                             fmaxf(V1.z + Eq[6],  V1.w + Eq[7]));
            float mC = fmaxf(fmaxf(V2.x + Eq[8],  V2.y + Eq[9]),
                             fmaxf(V2.z + Eq[10], V2.w + Eq[11]));
            float mD = fmaxf(fmaxf(V3.x + Eq[12], V3.y + Eq[13]),
                             fmaxf(V3.z + Eq[14], V3.w + Eq[15]));
            float Mq = fmaxf(fmaxf(mA, mB), fmaxf(mC, mD));
            float u = fmaxf(Mq, dpp_mov_f<0xB1>(Mq));
            float M = fmaxf(u, dpp_mov_f<0x4E>(u));
            float vn = M + etj;
            if (t < seq_len) v = vn;
            if (q == 0) { vstep[wp][j] = v; vhist[t * K_ + j] = v; }
        }
        __syncthreads();
    }

    // ---- epilogue ----
    if (fwd) {
        float pm = (q == 0) ? p : 0.f;
#pragma unroll
        for (int m = 32; m; m >>= 1) pm += __shfl_xor(pm, m, 64);
        if (lane == 0) red[wv] = pm;
    }
    __syncthreads();
    if (wv == 0) {
        float rs = (red[0] + red[1]) + (red[2] + red[3]);
        float log_norm = C + __logf(rs);
        // sequence score (lane-parallel over t)
        float sc = 0.f;
#pragma unroll
        for (int k = 0; k < 4; ++k) {
            int t = lane + k * 64;
            if (t < seq_len) {
                int tg = target[b * T_ + t];
                sc += ebuf[t * K_ + tg];
                if (t >= 1) sc += trans[target[b * T_ + t - 1] * K_ + tg];
            }
        }
#pragma unroll
        for (int m = 32; m; m >>= 1) sc += __shfl_xor(sc, m, 64);
        if (lane == 0) out[BT_ + b] = sc - log_norm;
    } else if (wv == 4) {
        // backtrack: identical to the proven round-0 code, v from vhist
        float vfin = vhist[(T_ - 1) * K_ + lane];
        float M = wave_max64(vfin);
        unsigned long long ball = __ballot(vfin >= M);
        int tag = (int)__builtin_ctzll(ball);

        int path[4];
#pragma unroll
        for (int k = 0; k < 4; ++k) path[k] = 0;
        if (lane == ((T_ - 1) & 63)) path[(T_ - 1) >> 6] = tag;

        float vpre = vhist[(T_ - 2) * K_ + lane];
        for (int t = T_ - 1; t >= 1; --t) {
            float vnext = (t >= 2) ? vhist[(t - 2) * K_ + lane] : 0.f;
            if (t < seq_len) {
                float s = vpre + tbuf[lane * 65 + tag];
                float Ms = wave_max64(s);
                unsigned long long bl = __ballot(s >= Ms);
                tag = (int)__builtin_ctzll(bl);
            }
            int pidx = t - 1;
            if (lane == (pidx & 63)) path[pidx >> 6] = tag;
            vpre = vnext;
        }
#pragma unroll
        for (int k = 0; k < 4; ++k) {
            int t = lane + k * 64;
            out[b * T_ + t] = (t < seq_len) ? (float)path[k] : 0.f;
        }
    }
}

// ---------------------------------------------------------------------------
extern "C" void kernel_launch(void* const* d_in, const int* in_sizes, int n_in,
                              void* d_out, int out_size, void* d_ws, size_t ws_size,
                              hipStream_t stream) {
    const float* hidden = (const float*)d_in[0];
    const int* masks    = (const int*)d_in[1];
    const int* target   = (const int*)d_in[2];
    const float* W      = (const float*)d_in[3];
    const float* bias   = (const float*)d_in[4];
    const float* trans  = (const float*)d_in[5];
    float* out = (float*)d_out;
    float* emis = (float*)d_ws;

    gemm_emis<<<dim3(BT_ / BM_), dim3(256), 0, stream>>>(hidden, W, bias, emis);
    crf_kernel<<<dim3(B_), dim3(512), 0, stream>>>(emis, masks, target, trans, out);
}